// Round 4
// baseline (63.316 us; speedup 1.0000x reference)
//
#include <hip/hip_runtime.h>
#include <math.h>

// ---- problem constants ----
#define L_IN   2560000
#define HOP    512
#define NB     84
#define NF     5000
#define PAD0   6726                    // wl0 = 13453, pad = wl0//2
#define XPLEN  2573452                 // L + 2*PAD0 (valid reflect region)
#define XBLEN  2634496                 // bf16 signal taps (mult 256), covers nt=39 window
#define NT2    40                      // frame tiles of 128 (5120 frames)
#define CSLOTS 12                      // k-chunk slots per frame tile
#define NBLK   (NT2*CSLOTS)            // 480 blocks
#define TSTEPS 251                     // total A k-steps: 211 + 34 + 6

#define XB_NB  10291                   // XBLEN/256
#define AG_NB  502                     // 251*512/256

#define LDS_SZ 133376                  // >= 130048 + 24*128 stage; >= 131072 epilogue

// ---- workspace layout (bytes) ----
#define XB_B 0
#define AG_B 5268992                   // XBLEN*2
#define P_B  7325184                   // AG_B + 251*8192

typedef short bf16x4 __attribute__((ext_vector_type(4)));
typedef short bf16x8 __attribute__((ext_vector_type(8)));
typedef float f32x16 __attribute__((ext_vector_type(16)));

__device__ inline unsigned short f2bf(float f) {
  unsigned int u = __float_as_uint(f);
  return (unsigned short)((u + 0x7fffu + ((u >> 16) & 1u)) >> 16);
}

// chunk slot -> (mtile, chunk idx, steps); long chunks first for LPT scheduling
__device__ inline void cparams(int c, int& mt, int& ck, int& steps) {
  if (c < 8)       { mt = 0; ck = c; steps = 24; }
  else if (c == 8) { mt = 1; ck = 0; steps = 24; }
  else if (c == 9) { mt = 0; ck = 8; steps = 19; }
  else if (c ==10) { mt = 1; ck = 1; steps = 10; }
  else             { mt = 2; ck = 0; steps = 6;  }
}
__device__ inline int kstart(int mt) { return mt == 0 ? 0 : (mt == 1 ? 5632 : 6528); }
__device__ inline int mtstep(int mt) { return mt == 0 ? 0 : (mt == 1 ? 211 : 245); }

// fused: xb (reflect-pad + bf16) and A in exact per-wave fragment order
// A layout: [step s][im 2][kk 4][lane 64][j 8] bf16
__global__ __launch_bounds__(256) void k_prep(const float* __restrict__ x,
                                              unsigned short* __restrict__ xb,
                                              unsigned short* __restrict__ Ag) {
  if (blockIdx.x < XB_NB) {
    int i = blockIdx.x * 256 + threadIdx.x;
    float v = 0.f;
    if (i < XPLEN) {
      int u = i - PAD0;
      if (u < 0) u = -u;
      else if (u >= L_IN) u = 2 * L_IN - 2 - u;
      v = x[u];
    }
    xb[i] = f2bf(v);
  } else {
    int g = (blockIdx.x - XB_NB) * 256 + threadIdx.x;   // < 128512
    int s = g >> 9, w = g & 511;
    int im = w >> 8, kk = (w >> 6) & 3, lane = w & 63;
    int mt = (s < 211) ? 0 : ((s < 245) ? 1 : 2);
    int ksl = s - mtstep(mt);
    int tap0 = kstart(mt) + ksl * 64 + kk * 16 + ((lane >> 5) << 3);
    int row = im * 32 + (lane & 31);
    int bin = mt * 32 + (row >> 1);
    bf16x8 vv;
    if (bin >= NB) {
#pragma unroll
      for (int j = 0; j < 8; ++j) vv[j] = 0;
    } else {
      double q    = 1.0 / (pow(2.0, 1.0 / 12.0) - 1.0);
      double freq = 20.0 * pow(2.0, (double)bin / 12.0);
      int wl = (int)(16000.0 * q / freq);
      if (wl > L_IN / 4) wl = L_IN / 4;
      int pad = wl >> 1;
      int fbq = (int)(freq * (double)wl / 16000.0);
      if (fbq > wl / 2) fbq = wl / 2;
      int isIm = row & 1;
#pragma unroll
      for (int j = 0; j < 8; ++j) {
        int n = tap0 + j - (PAD0 - pad);
        float v = 0.f;
        if (n >= 0 && n < wl && wl >= 32) {
          float wn = 0.5f - 0.5f * cosf(6.28318530717958647f * ((float)n / (float)wl));
          double m = fmod((double)fbq * (double)n, (double)wl);
          float a  = (float)(6.283185307179586476925 * (m / (double)wl));
          v = isIm ? (-wn * sinf(a)) : (wn * cosf(a));
        }
        vv[j] = (short)f2bf(v);
      }
    }
    *(bf16x8*)(Ag + ((size_t)s * 4096 + im * 2048 + kk * 512 + lane * 8)) = vv;
  }
}

struct AF { bf16x8 f[2][4]; };

__device__ inline void loadA(AF& a, const char* Aw, int ksl, int lane) {
  const char* p = Aw + ((size_t)ksl << 13) + lane * 16;
#pragma unroll
  for (int im = 0; im < 2; ++im)
#pragma unroll
    for (int kk = 0; kk < 4; ++kk)
      a.f[im][kk] = *(const bf16x8*)(p + im * 4096 + kk * 1024);
}

__device__ inline void stepC(const AF& a, int ksl, int lane, const char* Bw,
                             f32x16 acc[2][4]) {
  bf16x8 bf[4][4];
  int tb = ksl * 128 + ((lane >> 5) << 4);         // tap byte base
#pragma unroll
  for (int in_ = 0; in_ < 4; ++in_) {
    int fl = in_ * 32 + (lane & 31);
    int ob = fl * 1024 + tb;
#pragma unroll
    for (int kk = 0; kk < 4; ++kk) {
      int o = ob + kk * 32;
      int sw = ((o >> 10) & 15) << 3;
      int lo = o ^ sw;
      bf16x4 l4 = *(const bf16x4*)(Bw + lo);
      bf16x4 h4 = *(const bf16x4*)(Bw + (lo ^ 8));
      bf[in_][kk] = __builtin_shufflevector(l4, h4, 0, 1, 2, 3, 4, 5, 6, 7);
    }
  }
#pragma unroll
  for (int kk = 0; kk < 4; ++kk)
#pragma unroll
    for (int im = 0; im < 2; ++im)
#pragma unroll
      for (int in_ = 0; in_ < 4; ++in_)
        acc[im][in_] = __builtin_amdgcn_mfma_f32_32x32x16_bf16(
            a.f[im][kk], bf[in_][kk], acc[im][in_], 0, 0, 0);
}

// block = 64 rows x 128 frames x one k-chunk; 4 waves interleaved K-split.
// B window LDS-resident; A direct L2->reg in fragment order.
__global__ __launch_bounds__(256, 1) void k_gemm(const unsigned short* __restrict__ Ag,
                                                 const unsigned short* __restrict__ xb,
                                                 float* __restrict__ P) {
  extern __shared__ char lds[];
  const int tid = threadIdx.x, lane = tid & 63, wv = tid >> 6;

  int bid = blockIdx.x;
  int lid = (bid & 7) * 60 + (bid >> 3);           // XCD-chunked bijective (480%8==0)
  int nt = lid / 12, c = lid - nt * 12;
  int mt, ck, steps; cparams(c, mt, ck, steps);
  int kbase = kstart(mt) + ck * 1536;              // window start tap (mult 64)
  int wbytes = 130048 + steps * 128;

  // ---- stage B window, 8B-granular XOR swizzle ----
  const char* xsrc = (const char*)xb + ((size_t)(nt * 65536 + kbase) * 2);
  for (int u = tid; u * 16 < wbytes; u += 256) {
    int o = u * 16;
    uint4 v = *(const uint4*)(xsrc + o);
    int sw = ((o >> 10) & 15) << 3;
    *(uint2*)(lds + (o ^ sw))       = make_uint2(v.x, v.y);
    *(uint2*)(lds + ((o + 8) ^ sw)) = make_uint2(v.z, v.w);
  }
  __syncthreads();

  f32x16 acc[2][4];
#pragma unroll
  for (int i = 0; i < 2; ++i)
#pragma unroll
    for (int j = 0; j < 4; ++j)
#pragma unroll
      for (int e = 0; e < 16; ++e) acc[i][j][e] = 0.f;

  const char* Aw = (const char*)Ag + ((size_t)(mtstep(mt) + ck * 24) << 13);
  int nks = (steps - wv + 3) >> 2;                 // interleaved split: ksl = wv+4i

  AF fa, fb2;
  loadA(fa, Aw, wv, lane);
  int i = 0;
  for (; i + 2 <= nks; i += 2) {
    loadA(fb2, Aw, wv + 4 * (i + 1), lane);
    stepC(fa, wv + 4 * i, lane, lds, acc);
    int nx = (i + 2 < nks) ? (i + 2) : (i + 1);    // dummy reload at tail
    loadA(fa, Aw, wv + 4 * nx, lane);
    stepC(fb2, wv + 4 * (i + 1), lane, lds, acc);
  }
  if (i < nks) stepC(fa, wv + 4 * i, lane, lds, acc);

  // ---- epilogue: cross-wave reduce in LDS (reuse B window), write partials ----
  __syncthreads();
  float* Cw = (float*)(lds + wv * 32768);
#pragma unroll
  for (int im = 0; im < 2; ++im)
#pragma unroll
    for (int in_ = 0; in_ < 4; ++in_) {
      f32x16 v = acc[im][in_];
      int col = in_ * 32 + (lane & 31);
      int rb  = im * 32 + ((lane >> 5) << 2);
#pragma unroll
      for (int r = 0; r < 16; ++r) {
        int row = rb + (r & 3) + 8 * (r >> 2);
        Cw[row * 128 + col] = v[r];
      }
    }
  __syncthreads();
  float* Pb = P + ((size_t)(nt * 12 + c) << 13);
  const float* L0 = (const float*)lds;
#pragma unroll
  for (int e = 0; e < 32; ++e) {
    int idx = e * 256 + tid;
    Pb[idx] = L0[idx] + L0[idx + 8192] + L0[idx + 16384] + L0[idx + 24576];
  }
}

// reduce partials over k-chunks + magnitude
__global__ __launch_bounds__(256) void k_mag(const float* __restrict__ P,
                                             float* __restrict__ out) {
  int col = blockIdx.x * 256 + threadIdx.x;
  int b = blockIdx.y;
  if (col >= NF) return;
  int mt = b >> 5;
  int rl = (2 * b) & 63;
  int nt = col >> 7, fl = col & 127;
  float re = 0.f, iv = 0.f;
#pragma unroll
  for (int c = 0; c < 12; ++c) {
    int cmt = (c < 8 || c == 9) ? 0 : ((c == 8 || c == 10) ? 1 : 2);
    if (cmt != mt) continue;
    const float* Pb = P + ((size_t)(nt * 12 + c) << 13);
    re += Pb[(rl << 7) + fl];
    iv += Pb[((rl + 1) << 7) + fl];
  }
  out[(size_t)b * NF + col] = sqrtf(re * re + iv * iv);
}

extern "C" void kernel_launch(void* const* d_in, const int* in_sizes, int n_in,
                              void* d_out, int out_size, void* d_ws, size_t ws_size,
                              hipStream_t stream) {
  const float* x = (const float*)d_in[0];
  char* ws = (char*)d_ws;
  unsigned short* xb = (unsigned short*)(ws + XB_B);
  unsigned short* Ag = (unsigned short*)(ws + AG_B);
  float* P           = (float*)(ws + P_B);
  float* out = (float*)d_out;

  hipFuncSetAttribute((const void*)k_gemm,
                      hipFuncAttributeMaxDynamicSharedMemorySize, LDS_SZ);

  hipLaunchKernelGGL(k_prep, dim3(XB_NB + AG_NB), dim3(256), 0, stream, x, xb, Ag);
  hipLaunchKernelGGL(k_gemm, dim3(NBLK), dim3(256), LDS_SZ, stream, Ag, xb, P);
  hipLaunchKernelGGL(k_mag, dim3(20, NB), dim3(256), 0, stream, P, out);
}

// Round 5
// 46.002 us; speedup vs baseline: 1.3764x; 1.3764x over previous
//
#include <hip/hip_runtime.h>
#include <math.h>

// ---- problem constants ----
#define L_IN   2560000
#define HOP    512
#define NB     84
#define NF     5000
#define PAD0   6726                    // wl0 = 13453, pad = wl0//2
#define XPLEN  2573452                 // L + 2*PAD0 (valid reflect region)
#define XBLEN  2634496                 // bf16 signal taps (mult 256)
#define NTIL   80                      // frame tiles of 64 (5120 frames)
#define SLOTS  7                       // k-chunk slots per frame tile
#define NBLK   (NTIL*SLOTS)            // 560 blocks
#define TSTEPS 251                     // total A k-steps: 211 + 34 + 6

#define XB_NB  10291                   // XBLEN/256
#define AG_NB  502                     // 251*512/256

#define LDS_SZ 70656                   // >= max window 70016; >= 65536 epilogue

// ---- workspace layout (bytes) ----
#define XB_B 0
#define AG_B 5268992                   // XBLEN*2
#define P_B  7325184                   // AG_B + 251*8192; P = 560*16KB = 8.75MB

typedef short bf16x4 __attribute__((ext_vector_type(4)));
typedef short bf16x8 __attribute__((ext_vector_type(8)));
typedef float f32x16 __attribute__((ext_vector_type(16)));

__device__ inline unsigned short f2bf(float f) {
  unsigned int u = __float_as_uint(f);
  return (unsigned short)((u + 0x7fffu + ((u >> 16) & 1u)) >> 16);
}

// slot -> (m-tile, global step start, steps, tap base)
__device__ inline void cparams(int c, int& mt, int& gs, int& ns, int& kb) {
  // mt0 split {43,42,42,42,42}; mt1 whole (34); mt2 whole (6)
  const int gs_[7] = {0, 43, 85, 127, 169, 211, 245};
  const int ns_[7] = {43, 42, 42, 42, 42, 34, 6};
  const int mt_[7] = {0, 0, 0, 0, 0, 1, 2};
  const int kb_[7] = {0, 2752, 5440, 8128, 10816, 5632, 6528};
  mt = mt_[c]; gs = gs_[c]; ns = ns_[c]; kb = kb_[c];
}

// fused: xb (reflect-pad + bf16) and A in exact per-wave fragment order
// A layout: [step s][im 2][kk 4][lane 64][j 8] bf16
__global__ __launch_bounds__(256) void k_prep(const float* __restrict__ x,
                                              unsigned short* __restrict__ xb,
                                              unsigned short* __restrict__ Ag) {
  if (blockIdx.x < XB_NB) {
    int i = blockIdx.x * 256 + threadIdx.x;
    float v = 0.f;
    if (i < XPLEN) {
      int u = i - PAD0;
      if (u < 0) u = -u;
      else if (u >= L_IN) u = 2 * L_IN - 2 - u;
      v = x[u];
    }
    xb[i] = f2bf(v);
  } else {
    int g = (blockIdx.x - XB_NB) * 256 + threadIdx.x;   // < 128512
    int s = g >> 9, w = g & 511;
    int im = w >> 8, kk = (w >> 6) & 3, lane = w & 63;
    int mt = (s < 211) ? 0 : ((s < 245) ? 1 : 2);
    int mst = (mt == 0) ? 0 : ((mt == 1) ? 211 : 245);
    int kst = (mt == 0) ? 0 : ((mt == 1) ? 5632 : 6528);
    int ksl = s - mst;
    int tap0 = kst + ksl * 64 + kk * 16 + ((lane >> 5) << 3);
    int row = im * 32 + (lane & 31);
    int bin = mt * 32 + (row >> 1);
    bf16x8 vv;
    if (bin >= NB) {
#pragma unroll
      for (int j = 0; j < 8; ++j) vv[j] = 0;
    } else {
      double q    = 1.0 / (pow(2.0, 1.0 / 12.0) - 1.0);
      double freq = 20.0 * pow(2.0, (double)bin / 12.0);
      int wl = (int)(16000.0 * q / freq);
      if (wl > L_IN / 4) wl = L_IN / 4;
      int pad = wl >> 1;
      int fbq = (int)(freq * (double)wl / 16000.0);
      if (fbq > wl / 2) fbq = wl / 2;
      int isIm = row & 1;
#pragma unroll
      for (int j = 0; j < 8; ++j) {
        int n = tap0 + j - (PAD0 - pad);
        float v = 0.f;
        if (n >= 0 && n < wl && wl >= 32) {
          float wn = 0.5f - 0.5f * cosf(6.28318530717958647f * ((float)n / (float)wl));
          double m = fmod((double)fbq * (double)n, (double)wl);
          float a  = (float)(6.283185307179586476925 * (m / (double)wl));
          v = isIm ? (-wn * sinf(a)) : (wn * cosf(a));
        }
        vv[j] = (short)f2bf(v);
      }
    }
    *(bf16x8*)(Ag + ((size_t)s * 4096 + im * 2048 + kk * 512 + lane * 8)) = vv;
  }
}

struct AF { bf16x8 f[2][4]; };

__device__ inline void loadA(AF& a, const char* Ag, int s, int lane) {
  const char* p = Ag + ((size_t)s << 13) + lane * 16;
#pragma unroll
  for (int im = 0; im < 2; ++im)
#pragma unroll
    for (int kk = 0; kk < 4; ++kk)
      a.f[im][kk] = *(const bf16x8*)(p + im * 4096 + kk * 1024);
}

// one K-step (64 taps) x 64 frames for this wave's 64x64 output tile
__device__ inline void stepC(const AF& a, int l, int lane, const char* Bw,
                             f32x16 acc[2][2]) {
  bf16x8 bf[2][2][4];
  int tb = l * 128 + ((lane >> 5) << 4);           // tap byte base
#pragma unroll
  for (int in_ = 0; in_ < 2; ++in_) {
    int fl = in_ * 32 + (lane & 31);
    int ob = fl * 1024 + tb;
#pragma unroll
    for (int kk = 0; kk < 4; ++kk) {
      int o = ob + kk * 32;
      int sw = ((o >> 10) & 15) << 3;
      int lo = o ^ sw;
      bf16x4 l4 = *(const bf16x4*)(Bw + lo);
      bf16x4 h4 = *(const bf16x4*)(Bw + (lo ^ 8));
      bf[in_][0][kk] = __builtin_shufflevector(l4, h4, 0, 1, 2, 3, 4, 5, 6, 7);
    }
  }
#pragma unroll
  for (int kk = 0; kk < 4; ++kk)
#pragma unroll
    for (int im = 0; im < 2; ++im)
#pragma unroll
      for (int in_ = 0; in_ < 2; ++in_)
        acc[im][in_] = __builtin_amdgcn_mfma_f32_32x32x16_bf16(
            a.f[im][kk], bf[in_][0][kk], acc[im][in_], 0, 0, 0);
}

// block = 64 rows x 64 frames x one k-chunk; 4 waves K-split (interleaved).
// B window LDS-resident; A direct L2->reg in fragment order. 2 blocks/CU.
__global__ __launch_bounds__(256, 2) void k_gemm(const unsigned short* __restrict__ Ag,
                                                 const unsigned short* __restrict__ xb,
                                                 float* __restrict__ P) {
  extern __shared__ char lds[];
  const int tid = threadIdx.x, lane = tid & 63, wv = tid >> 6;

  int bid = blockIdx.x;
  int lid = (bid & 7) * (NBLK / 8) + (bid >> 3);   // XCD-chunked bijective (560%8==0)
  int nt = lid / SLOTS, c = lid - nt * SLOTS;
  int mt, gs, ns, kb; cparams(c, mt, gs, ns, kb);
  int wbytes = 64512 + 128 * ns;                   // (63*512 + ns*64)*2

  // ---- stage B window, 8B-granular XOR swizzle ----
  const char* xsrc = (const char*)xb + (size_t)nt * 65536 + (size_t)kb * 2;
  for (int u = tid; u * 16 < wbytes; u += 256) {
    int o = u * 16;
    uint4 v = *(const uint4*)(xsrc + o);
    int sw = ((o >> 10) & 15) << 3;
    *(uint2*)(lds + (o ^ sw))       = make_uint2(v.x, v.y);
    *(uint2*)(lds + ((o + 8) ^ sw)) = make_uint2(v.z, v.w);
  }

  f32x16 acc[2][2];
#pragma unroll
  for (int i = 0; i < 2; ++i)
#pragma unroll
    for (int j = 0; j < 2; ++j)
#pragma unroll
      for (int e = 0; e < 16; ++e) acc[i][j][e] = 0.f;

  const char* Ab = (const char*)Ag;
  int nks = (ns - wv + 3) >> 2;                    // wave's steps: l = wv + 4i

  AF fa, fb2;
  loadA(fa, Ab, gs + wv, lane);                    // prefetch overlaps stage
  __syncthreads();                                 // B window resident

  int i = 0;
  for (; i + 2 <= nks; i += 2) {
    loadA(fb2, Ab, gs + wv + 4 * (i + 1), lane);
    stepC(fa, wv + 4 * i, lane, lds, acc);
    int nx = (i + 2 < nks) ? (i + 2) : (i + 1);    // dummy reload at tail
    loadA(fa, Ab, gs + wv + 4 * nx, lane);
    stepC(fb2, wv + 4 * (i + 1), lane, lds, acc);
  }
  if (i < nks) stepC(fa, wv + 4 * i, lane, lds, acc);

  // ---- epilogue: cross-wave reduce in LDS (reuse B window), write partials ----
  __syncthreads();
  float* Cw = (float*)(lds + wv * 16384);
#pragma unroll
  for (int im = 0; im < 2; ++im)
#pragma unroll
    for (int in_ = 0; in_ < 2; ++in_) {
      f32x16 v = acc[im][in_];
      int col = in_ * 32 + (lane & 31);
      int rb  = im * 32 + ((lane >> 5) << 2);
#pragma unroll
      for (int r = 0; r < 16; ++r) {
        int row = rb + (r & 3) + 8 * (r >> 2);
        Cw[row * 64 + col] = v[r];
      }
    }
  __syncthreads();
  float* Pb = P + ((size_t)(nt * SLOTS + c) << 12);
  const float* L0 = (const float*)lds;
#pragma unroll
  for (int e = 0; e < 16; ++e) {
    int idx = e * 256 + tid;
    Pb[idx] = L0[idx] + L0[idx + 4096] + L0[idx + 8192] + L0[idx + 12288];
  }
}

// reduce partials over k-chunks + magnitude
__global__ __launch_bounds__(256) void k_mag(const float* __restrict__ P,
                                             float* __restrict__ out) {
  int col = blockIdx.x * 256 + threadIdx.x;
  int b = blockIdx.y;
  if (col >= NF) return;
  int mt = b >> 5;
  int rl = (2 * b) & 63;
  int nt = col >> 6, fl = col & 63;
  const float* Pt = P + ((size_t)(nt * SLOTS) << 12);
  float re = 0.f, iv = 0.f;
  if (mt == 0) {
#pragma unroll
    for (int c = 0; c < 5; ++c) {
      const float* Pb = Pt + ((size_t)c << 12);
      re += Pb[(rl << 6) + fl];
      iv += Pb[((rl + 1) << 6) + fl];
    }
  } else {
    const float* Pb = Pt + ((size_t)(mt + 4) << 12);   // slot 5 or 6
    re = Pb[(rl << 6) + fl];
    iv = Pb[((rl + 1) << 6) + fl];
  }
  out[(size_t)b * NF + col] = sqrtf(re * re + iv * iv);
}

extern "C" void kernel_launch(void* const* d_in, const int* in_sizes, int n_in,
                              void* d_out, int out_size, void* d_ws, size_t ws_size,
                              hipStream_t stream) {
  const float* x = (const float*)d_in[0];
  char* ws = (char*)d_ws;
  unsigned short* xb = (unsigned short*)(ws + XB_B);
  unsigned short* Ag = (unsigned short*)(ws + AG_B);
  float* P           = (float*)(ws + P_B);
  float* out = (float*)d_out;

  hipFuncSetAttribute((const void*)k_gemm,
                      hipFuncAttributeMaxDynamicSharedMemorySize, LDS_SZ);

  hipLaunchKernelGGL(k_prep, dim3(XB_NB + AG_NB), dim3(256), 0, stream, x, xb, Ag);
  hipLaunchKernelGGL(k_gemm, dim3(NBLK), dim3(256), LDS_SZ, stream, Ag, xb, P);
  hipLaunchKernelGGL(k_mag, dim3(20, NB), dim3(256), 0, stream, P, out);
}

// Round 6
// 33.141 us; speedup vs baseline: 1.9105x; 1.3880x over previous
//
#include <hip/hip_runtime.h>
#include <math.h>

// ---- problem constants ----
#define L_IN   2560000
#define HOP    512
#define NB     84
#define NF     5000
#define PAD0   6726                    // wl0 = 13453, pad = wl0//2
#define XPLEN  2573452                 // L + 2*PAD0 (valid reflect region)
#define XBLEN2 2637824                 // bf16 taps, mult 2048, pads DMA overreach
#define NTIL   80                      // frame tiles of 64
#define SLOTS  7                       // k-chunk slots per frame tile
#define NBLK   (NTIL*SLOTS)            // 560
#define TSTEPS 251                     // global A k-steps: 211 + 34 + 6

#define XB_NB  1288                    // XBLEN2 / 2048
#define AG_NB  502                     // 251*512/256

#define LDS_SZ 70656                   // 69 DMA chunks * 1024; >= 65536 epilogue

// ---- workspace layout (bytes) ----
#define XB_B 0
#define AG_B 5275648                   // XBLEN2*2
#define P_B  7331840                   // AG_B + 251*8192 ; P = 80*5*16KB = 6.25MB

typedef short bf16x8 __attribute__((ext_vector_type(8)));
typedef float f32x16 __attribute__((ext_vector_type(16)));

__device__ inline unsigned short f2bf(float f) {
  unsigned int u = __float_as_uint(f);
  return (unsigned short)((u + 0x7fffu + ((u >> 16) & 1u)) >> 16);
}

__device__ inline void load16(void* l, const void* g) {
  __builtin_amdgcn_global_load_lds((const __attribute__((address_space(1))) void*)g,
                                   (__attribute__((address_space(3))) void*)l, 16, 0, 0);
}

// fused: xb (reflect-pad + bf16, 8/thread) and A in per-wave fragment order
// A layout: [step s][im 2][kk 4][lane 64][j 8] bf16
__global__ __launch_bounds__(256) void k_prep(const float* __restrict__ x,
                                              unsigned short* __restrict__ xb,
                                              unsigned short* __restrict__ Ag) {
  if (blockIdx.x < XB_NB) {
    int i8 = (blockIdx.x * 256 + threadIdx.x) * 8;
    bf16x8 o;
    int u0 = i8 - PAD0;
    if (u0 >= 0 && u0 + 8 <= L_IN) {                 // interior fast path
      const float2* p = (const float2*)(x + u0);     // u0 even -> 8B aligned
#pragma unroll
      for (int j = 0; j < 4; ++j) {
        float2 v = p[j];
        o[2 * j]     = (short)f2bf(v.x);
        o[2 * j + 1] = (short)f2bf(v.y);
      }
    } else {
#pragma unroll
      for (int j = 0; j < 8; ++j) {
        int i = i8 + j;
        float v = 0.f;
        if (i < XPLEN) {
          int u = i - PAD0;
          if (u < 0) u = -u;
          else if (u >= L_IN) u = 2 * L_IN - 2 - u;
          v = x[u];
        }
        o[j] = (short)f2bf(v);
      }
    }
    *(bf16x8*)(xb + i8) = o;
  } else {
    int g = (blockIdx.x - XB_NB) * 256 + threadIdx.x;   // < 128512
    int s = g >> 9, w = g & 511;
    int im = w >> 8, kk = (w >> 6) & 3, lane = w & 63;
    int mt  = (s < 211) ? 0 : ((s < 245) ? 1 : 2);
    int mst = (mt == 0) ? 0 : ((mt == 1) ? 211 : 245);
    int kst = (mt == 0) ? 0 : ((mt == 1) ? 5632 : 6528);
    int tap0 = kst + (s - mst) * 64 + kk * 16 + ((lane >> 5) << 3);
    int row = im * 32 + (lane & 31);
    int bin = mt * 32 + (row >> 1);
    bf16x8 vv;
    if (bin >= NB) {
#pragma unroll
      for (int j = 0; j < 8; ++j) vv[j] = 0;
    } else {
      double q    = 1.0 / (pow(2.0, 1.0 / 12.0) - 1.0);
      double freq = 20.0 * pow(2.0, (double)bin / 12.0);
      int wl = (int)(16000.0 * q / freq);
      if (wl > L_IN / 4) wl = L_IN / 4;
      int pad = wl >> 1;
      int fbq = (int)(freq * (double)wl / 16000.0);
      if (fbq > wl / 2) fbq = wl / 2;
      int isIm = row & 1;
      float invwl = 1.0f / (float)wl;
#pragma unroll
      for (int j = 0; j < 8; ++j) {
        int n = tap0 + j - (PAD0 - pad);
        float v = 0.f;
        if (n >= 0 && n < wl) {                      // all bins have wl>=111
          float wn = 0.5f - 0.5f * cosf(6.2831853071795865f * ((float)n * invwl));
          int m = (fbq * n) % wl;                    // fbq*n < 2.2e5, exact
          float a = 6.2831853071795865f * ((float)m * invwl);
          v = isIm ? (-wn * sinf(a)) : (wn * cosf(a));
        }
        vv[j] = (short)f2bf(v);
      }
    }
    *(bf16x8*)(Ag + ((size_t)s * 4096 + im * 2048 + kk * 512 + lane * 8)) = vv;
  }
}

struct AF { bf16x8 f[2][4]; };

__device__ inline void loadA(AF& a, const char* Ag, int s, int lane) {
  const char* p = Ag + ((size_t)s << 13) + lane * 16;
#pragma unroll
  for (int im = 0; im < 2; ++im)
#pragma unroll
    for (int kk = 0; kk < 4; ++kk)
      a.f[im][kk] = *(const bf16x8*)(p + im * 4096 + kk * 1024);
}

// one K-step (64 taps) x 64 frames; b128 B-reads with 16B-granular 4-bit XOR
__device__ inline void stepC(const AF& a, int l, int lane, const char* Bw,
                             f32x16 acc[2][2]) {
  bf16x8 bf[2][4];
  int tb = l * 128 + ((lane >> 5) << 4);
#pragma unroll
  for (int in_ = 0; in_ < 2; ++in_) {
    int ob = (in_ * 32 + (lane & 31)) * 1024 + tb;
#pragma unroll
    for (int kk = 0; kk < 4; ++kk) {
      int o = ob + kk * 32;
      o ^= ((o >> 10) & 15) << 4;
      bf[in_][kk] = *(const bf16x8*)(Bw + o);
    }
  }
  __builtin_amdgcn_s_setprio(1);
#pragma unroll
  for (int kk = 0; kk < 4; ++kk)
#pragma unroll
    for (int im = 0; im < 2; ++im)
#pragma unroll
      for (int in_ = 0; in_ < 2; ++in_)
        acc[im][in_] = __builtin_amdgcn_mfma_f32_32x32x16_bf16(
            a.f[im][kk], bf[in_][kk], acc[im][in_], 0, 0, 0);
  __builtin_amdgcn_s_setprio(0);
}

// block = 64 rows x 64 frames x one k-chunk; 4 waves K-split, depth-3 A pipe.
__global__ __launch_bounds__(256, 2) void k_gemm(const unsigned short* __restrict__ Ag,
                                                 const unsigned short* __restrict__ xb,
                                                 float* __restrict__ P,
                                                 float* __restrict__ out) {
  extern __shared__ char lds[];
  const int tid = threadIdx.x, lane = tid & 63, wv = tid >> 6;

  int bid = blockIdx.x;
  int lid = (bid & 7) * (NBLK / 8) + (bid >> 3);    // XCD-chunked bijective
  int nt = lid / SLOTS, c = lid - nt * SLOTS;
  const int gs_[7] = {0, 43, 85, 127, 169, 211, 245};
  const int ns_[7] = {43, 42, 42, 42, 42, 34, 6};
  const int kb_[7] = {0, 2752, 5440, 8128, 10816, 5632, 6528};
  int gs = gs_[c], ns = ns_[c], kb = kb_[c];
  int nch = (64512 + 128 * ns + 1023) >> 10;        // 1KB DMA chunks

  // ---- stage B window via global_load_lds, pre-swizzled (involutive) source ----
  const char* xsrc = (const char*)xb + (size_t)nt * 65536 + (size_t)kb * 2;
  for (int ci = wv; ci < nch; ci += 4)
    load16(lds + ci * 1024, xsrc + ci * 1024 + ((lane * 16) ^ ((ci & 15) << 4)));
  __builtin_amdgcn_sched_barrier(0);                // keep A-loads below DMAs

  const char* Ab = (const char*)Ag;
  int nks = (ns - wv + 3) >> 2;                     // wave steps: l = wv + 4i
  AF a0, a1, a2;
  int s0 = gs + wv, s1 = gs + wv + 4, s2 = gs + wv + 8;
  loadA(a0, Ab, s0 > 250 ? 250 : s0, lane);
  loadA(a1, Ab, s1 > 250 ? 250 : s1, lane);
  loadA(a2, Ab, s2 > 250 ? 250 : s2, lane);

  f32x16 acc[2][2];
#pragma unroll
  for (int i = 0; i < 2; ++i)
#pragma unroll
    for (int j = 0; j < 2; ++j)
#pragma unroll
      for (int e = 0; e < 16; ++e) acc[i][j][e] = 0.f;

  asm volatile("s_waitcnt vmcnt(24)" ::: "memory"); // all DMAs drained (24 A-loads newer)
  __syncthreads();

  int i = 0;
  while (i + 3 <= nks) {
    stepC(a0, wv + 4 * i, lane, lds, acc);
    if (i + 3 < nks) loadA(a0, Ab, gs + wv + 4 * (i + 3), lane);
    stepC(a1, wv + 4 * (i + 1), lane, lds, acc);
    if (i + 4 < nks) loadA(a1, Ab, gs + wv + 4 * (i + 4), lane);
    stepC(a2, wv + 4 * (i + 2), lane, lds, acc);
    if (i + 5 < nks) loadA(a2, Ab, gs + wv + 4 * (i + 5), lane);
    i += 3;
  }
  if (i < nks)     stepC(a0, wv + 4 * i, lane, lds, acc);
  if (i + 1 < nks) stepC(a1, wv + 4 * (i + 1), lane, lds, acc);
  if (i + 2 < nks) stepC(a2, wv + 4 * (i + 2), lane, lds, acc);

  // ---- epilogue: cross-wave reduce in LDS (window dead now) ----
  __syncthreads();
  float* Cw = (float*)(lds + wv * 16384);
#pragma unroll
  for (int im = 0; im < 2; ++im)
#pragma unroll
    for (int in_ = 0; in_ < 2; ++in_) {
      f32x16 v = acc[im][in_];
      int col = in_ * 32 + (lane & 31);
      int rb  = im * 32 + ((lane >> 5) << 2);
#pragma unroll
      for (int r = 0; r < 16; ++r) {
        int row = rb + (r & 3) + 8 * (r >> 2);
        Cw[row * 64 + col] = v[r];
      }
    }
  __syncthreads();
  const float* L0 = (const float*)lds;
  if (c < 5) {                                      // mt0: partial tile to P
    float* Pb = P + ((size_t)(nt * 5 + c) << 12);
#pragma unroll
    for (int e = 0; e < 16; ++e) {
      int idx = e * 256 + tid;
      Pb[idx] = L0[idx] + L0[idx + 4096] + L0[idx + 8192] + L0[idx + 12288];
    }
  } else {                                          // mt1/mt2: direct magnitude
    int bb = (c == 5) ? 32 : 64;
#pragma unroll
    for (int e = 0; e < 8; ++e) {
      int p = e * 256 + tid;                        // 2048 (bin,col) pairs
      int bl = p >> 6, fl = p & 63;
      int r0 = (bl * 2) * 64 + fl, r1 = r0 + 64;
      float re = L0[r0] + L0[r0 + 4096] + L0[r0 + 8192] + L0[r0 + 12288];
      float iv = L0[r1] + L0[r1 + 4096] + L0[r1 + 8192] + L0[r1 + 12288];
      int b = bb + bl, col = nt * 64 + fl;
      if (b < NB && col < NF)
        out[(size_t)b * NF + col] = sqrtf(re * re + iv * iv);
    }
  }
}

// reduce mt0 partials over 5 k-chunks + magnitude (bins 0..31)
__global__ __launch_bounds__(256) void k_mag(const float* __restrict__ P,
                                             float* __restrict__ out) {
  int col = blockIdx.x * 256 + threadIdx.x;
  int b = blockIdx.y;                               // 0..31
  if (col >= NF) return;
  int nt = col >> 6, fl = col & 63;
  const float* Pt = P + ((size_t)(nt * 5) << 12);
  float re = 0.f, iv = 0.f;
#pragma unroll
  for (int c = 0; c < 5; ++c) {
    const float* Pb = Pt + ((size_t)c << 12);
    re += Pb[(2 * b) * 64 + fl];
    iv += Pb[(2 * b + 1) * 64 + fl];
  }
  out[(size_t)b * NF + col] = sqrtf(re * re + iv * iv);
}

extern "C" void kernel_launch(void* const* d_in, const int* in_sizes, int n_in,
                              void* d_out, int out_size, void* d_ws, size_t ws_size,
                              hipStream_t stream) {
  const float* x = (const float*)d_in[0];
  char* ws = (char*)d_ws;
  unsigned short* xb = (unsigned short*)(ws + XB_B);
  unsigned short* Ag = (unsigned short*)(ws + AG_B);
  float* P           = (float*)(ws + P_B);
  float* out = (float*)d_out;

  hipFuncSetAttribute((const void*)k_gemm,
                      hipFuncAttributeMaxDynamicSharedMemorySize, LDS_SZ);

  hipLaunchKernelGGL(k_prep, dim3(XB_NB + AG_NB), dim3(256), 0, stream, x, xb, Ag);
  hipLaunchKernelGGL(k_gemm, dim3(NBLK), dim3(256), LDS_SZ, stream, Ag, xb, P, out);
  hipLaunchKernelGGL(k_mag, dim3(20, 32), dim3(256), 0, stream, P, out);
}

// Round 7
// 33.031 us; speedup vs baseline: 1.9169x; 1.0033x over previous
//
#include <hip/hip_runtime.h>
#include <math.h>

// ---- problem constants ----
#define L_IN   2560000
#define HOP    512
#define NB     84
#define NF     5000
#define PAD0   6726                    // wl0 = 13453, pad = wl0//2
#define XPLEN  2573452                 // L + 2*PAD0 (valid reflect region)
#define XBLEN2 2637824                 // bf16 taps, mult 2048, pads DMA overreach
#define NTIL   40                      // frame tiles of 128
#define SLOTS  6                       // k-chunk slots per frame tile
#define NBLK   (NTIL*SLOTS)            // 240 blocks -> single round on 256 CUs
#define XB_NB  1288                    // XBLEN2 / 2048
#define AG_NB  502                     // 251*512/256

#define LDS_SZ 137216                  // 134 DMA chunks * 1024 >= max window 136832
                                       // and >= 128 KB epilogue

// ---- workspace layout (bytes) ----
#define XB_B 0
#define AG_B 5275648                   // XBLEN2*2
#define P_B  7331840                   // AG_B + 251*8192 ; P = 40*4*32KB = 5.24MB

typedef short bf16x8 __attribute__((ext_vector_type(8)));
typedef float f32x16 __attribute__((ext_vector_type(16)));

__device__ inline unsigned short f2bf(float f) {
  unsigned int u = __float_as_uint(f);
  return (unsigned short)((u + 0x7fffu + ((u >> 16) & 1u)) >> 16);
}

__device__ inline void load16(void* l, const void* g) {
  __builtin_amdgcn_global_load_lds((const __attribute__((address_space(1))) void*)g,
                                   (__attribute__((address_space(3))) void*)l, 16, 0, 0);
}

// fused: xb (reflect-pad + bf16, 8/thread) and A in per-wave fragment order
// A layout: [step s][im 2][kk 4][lane 64][j 8] bf16
__global__ __launch_bounds__(256) void k_prep(const float* __restrict__ x,
                                              unsigned short* __restrict__ xb,
                                              unsigned short* __restrict__ Ag) {
  if (blockIdx.x < XB_NB) {
    int i8 = (blockIdx.x * 256 + threadIdx.x) * 8;
    bf16x8 o;
    int u0 = i8 - PAD0;
    if (u0 >= 0 && u0 + 8 <= L_IN) {                 // interior fast path
      const float2* p = (const float2*)(x + u0);     // u0 even -> 8B aligned
#pragma unroll
      for (int j = 0; j < 4; ++j) {
        float2 v = p[j];
        o[2 * j]     = (short)f2bf(v.x);
        o[2 * j + 1] = (short)f2bf(v.y);
      }
    } else {
#pragma unroll
      for (int j = 0; j < 8; ++j) {
        int i = i8 + j;
        float v = 0.f;
        if (i < XPLEN) {
          int u = i - PAD0;
          if (u < 0) u = -u;
          else if (u >= L_IN) u = 2 * L_IN - 2 - u;
          v = x[u];
        }
        o[j] = (short)f2bf(v);
      }
    }
    *(bf16x8*)(xb + i8) = o;
  } else {
    int g = (blockIdx.x - XB_NB) * 256 + threadIdx.x;   // < 128512
    int s = g >> 9, w = g & 511;
    int im = w >> 8, kk = (w >> 6) & 3, lane = w & 63;
    int mt  = (s < 211) ? 0 : ((s < 245) ? 1 : 2);
    int mst = (mt == 0) ? 0 : ((mt == 1) ? 211 : 245);
    int kst = (mt == 0) ? 0 : ((mt == 1) ? 5632 : 6528);
    int tap0 = kst + (s - mst) * 64 + kk * 16 + ((lane >> 5) << 3);
    int row = im * 32 + (lane & 31);
    int bin = mt * 32 + (row >> 1);
    bf16x8 vv;
    if (bin >= NB) {
#pragma unroll
      for (int j = 0; j < 8; ++j) vv[j] = 0;
    } else {
      double q    = 1.0 / (pow(2.0, 1.0 / 12.0) - 1.0);
      double freq = 20.0 * pow(2.0, (double)bin / 12.0);
      int wl = (int)(16000.0 * q / freq);
      if (wl > L_IN / 4) wl = L_IN / 4;
      int pad = wl >> 1;
      int fbq = (int)(freq * (double)wl / 16000.0);
      if (fbq > wl / 2) fbq = wl / 2;
      int isIm = row & 1;
      float invwl = 1.0f / (float)wl;
#pragma unroll
      for (int j = 0; j < 8; ++j) {
        int n = tap0 + j - (PAD0 - pad);
        float v = 0.f;
        if (n >= 0 && n < wl) {                      // all live bins have wl>=111
          float wn = 0.5f - 0.5f * cosf(6.2831853071795865f * ((float)n * invwl));
          int m = (fbq * n) % wl;                    // fbq*n < 2.2e5, exact in fp/int
          float a = 6.2831853071795865f * ((float)m * invwl);
          v = isIm ? (-wn * sinf(a)) : (wn * cosf(a));
        }
        vv[j] = (short)f2bf(v);
      }
    }
    *(bf16x8*)(Ag + ((size_t)s * 4096 + im * 2048 + kk * 512 + lane * 8)) = vv;
  }
}

struct AF { bf16x8 f[2][4]; };

__device__ inline void loadA(AF& a, const char* Ag, int s, int lane) {
  const char* p = Ag + ((size_t)s << 13) + lane * 16;
#pragma unroll
  for (int im = 0; im < 2; ++im)
#pragma unroll
    for (int kk = 0; kk < 4; ++kk)
      a.f[im][kk] = *(const bf16x8*)(p + im * 4096 + kk * 1024);
}

// one K-step (64 taps) x 128 frames; b128 B-reads, 16B-granular 4-bit XOR
__device__ inline void stepC(const AF& a, int l, int lane, const char* Bw,
                             f32x16 acc[2][4]) {
  int tb = l * 128 + ((lane >> 5) << 4);
#pragma unroll
  for (int n = 0; n < 4; ++n) {
    bf16x8 bf[4];
    int ob = (n * 32 + (lane & 31)) * 1024 + tb;
#pragma unroll
    for (int kk = 0; kk < 4; ++kk) {
      int o = ob + kk * 32;
      o ^= ((o >> 10) & 15) << 4;
      bf[kk] = *(const bf16x8*)(Bw + o);
    }
    __builtin_amdgcn_s_setprio(1);
#pragma unroll
    for (int kk = 0; kk < 4; ++kk) {
      acc[0][n] = __builtin_amdgcn_mfma_f32_32x32x16_bf16(a.f[0][kk], bf[kk], acc[0][n], 0, 0, 0);
      acc[1][n] = __builtin_amdgcn_mfma_f32_32x32x16_bf16(a.f[1][kk], bf[kk], acc[1][n], 0, 0, 0);
    }
    __builtin_amdgcn_s_setprio(0);
  }
}

// block = 64 rows x 128 frames x one k-chunk; 8 waves K-split (interleave 8).
// B window LDS-resident; A direct L2->reg in fragment order. 240 blocks.
__global__ __launch_bounds__(512, 2) void k_gemm(const unsigned short* __restrict__ Ag,
                                                 const unsigned short* __restrict__ xb,
                                                 float* __restrict__ P,
                                                 float* __restrict__ out) {
  extern __shared__ char lds[];
  const int tid = threadIdx.x, lane = tid & 63, wv = tid >> 6;

  int bid = blockIdx.x;
  int lid = (bid & 7) * (NBLK / 8) + (bid >> 3);    // XCD-chunked bijective
  int nt = lid / SLOTS, c = lid - nt * SLOTS;
  const int gs_[6] = {0, 53, 106, 159, 211, 245};
  const int ns_[6] = {53, 53, 53, 52, 34, 6};
  const int kb_[6] = {0, 3392, 6784, 10176, 5632, 6528};
  int gs = gs_[c], ns = ns_[c], kb = kb_[c];
  int nch = (130048 + 128 * ns + 1023) >> 10;       // 1KB DMA chunks (<=134)

  // ---- stage B window via global_load_lds, pre-swizzled (involutive) source ----
  const char* xsrc = (const char*)xb + (size_t)nt * 131072 + (size_t)kb * 2;
  for (int ci = wv; ci < nch; ci += 8)
    load16(lds + ci * 1024, xsrc + ci * 1024 + ((lane * 16) ^ ((ci & 15) << 4)));
  __builtin_amdgcn_sched_barrier(0);                // keep A-loads below DMAs

  const char* Ab = (const char*)Ag;
  int nks = (ns - wv + 7) >> 3;                     // wave steps: l = wv + 8i
  AF a0, a1;
  int s0 = gs + wv, s1 = gs + wv + 8;
  loadA(a0, Ab, s0 > 250 ? 250 : s0, lane);
  loadA(a1, Ab, s1 > 250 ? 250 : s1, lane);

  f32x16 acc[2][4];
#pragma unroll
  for (int i = 0; i < 2; ++i)
#pragma unroll
    for (int j = 0; j < 4; ++j)
#pragma unroll
      for (int e = 0; e < 16; ++e) acc[i][j][e] = 0.f;

  asm volatile("s_waitcnt vmcnt(16)" ::: "memory"); // DMAs drained (16 A-loads newer)
  __syncthreads();

  int i = 0;
  for (; i + 2 <= nks; i += 2) {
    stepC(a0, wv + 8 * i, lane, lds, acc);
    int sa = gs + wv + 8 * (i + 2); if (sa > 250) sa = 250;
    loadA(a0, Ab, sa, lane);
    stepC(a1, wv + 8 * (i + 1), lane, lds, acc);
    int sb = gs + wv + 8 * (i + 3); if (sb > 250) sb = 250;
    loadA(a1, Ab, sb, lane);
  }
  if (i < nks) stepC(a0, wv + 8 * i, lane, lds, acc);

  // ---- epilogue: 8-wave cross-reduce in LDS, two column-halves ----
  __syncthreads();                                  // window reads complete
  float* Pb = P + ((size_t)(nt * 4 + c) << 13);     // mt0 partial slot (c<4)
#pragma unroll
  for (int h = 0; h < 2; ++h) {
    float* Cw = (float*)(lds + wv * 16384);
#pragma unroll
    for (int im = 0; im < 2; ++im)
#pragma unroll
      for (int n2 = 0; n2 < 2; ++n2) {
        f32x16 v = acc[im][2 * h + n2];
        int col = n2 * 32 + (lane & 31);
        int rb  = im * 32 + ((lane >> 5) << 2);
#pragma unroll
        for (int r = 0; r < 16; ++r) {
          int row = rb + (r & 3) + 8 * (r >> 2);
          Cw[row * 64 + col] = v[r];
        }
      }
    __syncthreads();
    const float* L0 = (const float*)lds;
#pragma unroll
    for (int e = 0; e < 4; ++e) {
      int p = e * 512 + tid;                        // 2048 row-pairs
      int rp = p >> 6, cl = p & 63;
      float re = 0.f, iv = 0.f;
#pragma unroll
      for (int w = 0; w < 8; ++w) {
        re += L0[w * 4096 + (2 * rp) * 64 + cl];
        iv += L0[w * 4096 + (2 * rp + 1) * 64 + cl];
      }
      if (c < 4) {                                  // mt0: raw partial sums to P
        Pb[(2 * rp) * 128 + h * 64 + cl]     = re;
        Pb[(2 * rp + 1) * 128 + h * 64 + cl] = iv;
      } else {                                      // mt1/mt2: direct magnitude
        int b = ((c == 4) ? 32 : 64) + rp;
        int colg = nt * 128 + h * 64 + cl;
        if (b < NB && colg < NF)
          out[(size_t)b * NF + colg] = sqrtf(re * re + iv * iv);
      }
    }
    __syncthreads();                                // before next half's writes
  }
}

// reduce mt0 partials over 4 k-chunks + magnitude (bins 0..31)
__global__ __launch_bounds__(256) void k_mag(const float* __restrict__ P,
                                             float* __restrict__ out) {
  int col = blockIdx.x * 256 + threadIdx.x;
  int b = blockIdx.y;                               // 0..31
  if (col >= NF) return;
  int nt = col >> 7, cl = col & 127;
  const float* Pt = P + ((size_t)(nt * 4) << 13);
  float re = 0.f, iv = 0.f;
#pragma unroll
  for (int cc = 0; cc < 4; ++cc) {
    const float* Pbc = Pt + ((size_t)cc << 13);
    re += Pbc[(2 * b) * 128 + cl];
    iv += Pbc[(2 * b + 1) * 128 + cl];
  }
  out[(size_t)b * NF + col] = sqrtf(re * re + iv * iv);
}

extern "C" void kernel_launch(void* const* d_in, const int* in_sizes, int n_in,
                              void* d_out, int out_size, void* d_ws, size_t ws_size,
                              hipStream_t stream) {
  const float* x = (const float*)d_in[0];
  char* ws = (char*)d_ws;
  unsigned short* xb = (unsigned short*)(ws + XB_B);
  unsigned short* Ag = (unsigned short*)(ws + AG_B);
  float* P           = (float*)(ws + P_B);
  float* out = (float*)d_out;

  hipFuncSetAttribute((const void*)k_gemm,
                      hipFuncAttributeMaxDynamicSharedMemorySize, LDS_SZ);

  hipLaunchKernelGGL(k_prep, dim3(XB_NB + AG_NB), dim3(256), 0, stream, x, xb, Ag);
  hipLaunchKernelGGL(k_gemm, dim3(NBLK), dim3(512), LDS_SZ, stream, Ag, xb, P, out);
  hipLaunchKernelGGL(k_mag, dim3(20, 32), dim3(256), 0, stream, P, out);
}